// Round 3
// baseline (586.203 us; speedup 1.0000x reference)
//
#include <hip/hip_runtime.h>

// Elman RNN: h_{t+1} = tanh(x_t @ W_ih^T + b_ih + h @ W_hh^T + b_hh), T=512
// out = sigmoid(h_T @ fc_w^T + fc_b)
//
// Round 3: all-f32 formulation. One wave per sample (2048 waves, 2/SIMD);
// lane = hidden unit j; weights preloaded as f32 pairs in VGPRs; MACs via
// v_pk_fma_f32 (full-rate, 2 MACs/instr); h broadcast via v_readlane (f32,
// no fp16 repack, no ds_bpermute); x read through a wave-uniform pointer so
// the compiler emits s_load -> SGPR float4s feed pk_fma's scalar operand.

#define RN 2048
#define RT 512
#define RI 32
#define RH 64

typedef float f32x2 __attribute__((ext_vector_type(2)));

__device__ __forceinline__ float rl_f(float v, int lane) {
    return __builtin_bit_cast(float,
        __builtin_amdgcn_readlane(__builtin_bit_cast(int, v), lane));
}

__global__ __launch_bounds__(256, 2) void rnn_fused(
    const float* __restrict__ x,
    const float* __restrict__ W_ih,
    const float* __restrict__ W_hh,
    const float* __restrict__ b_ih,
    const float* __restrict__ b_hh,
    const float* __restrict__ fc_w,
    const float* __restrict__ fc_b,
    float* __restrict__ out)
{
    const int lane = threadIdx.x & 63;
    // force wave-uniformity so x addressing becomes scalar (s_load)
    const int wv = __builtin_amdgcn_readfirstlane((int)(threadIdx.x >> 6));
    const int n  = blockIdx.x * 4 + wv;

    // ---- preload weights (row `lane`) as f32 pairs in VGPRs ----
    f32x2 wih[RI / 2];
    {
        const f32x2* p = (const f32x2*)(W_ih + lane * RI);
#pragma unroll
        for (int m = 0; m < RI / 2; ++m) wih[m] = p[m];
    }
    f32x2 whh[RH / 2];
    {
        const f32x2* p = (const f32x2*)(W_hh + lane * RH);
#pragma unroll
        for (int q = 0; q < RH / 2; ++q) whh[q] = p[q];
    }
    const float bias = b_ih[lane] + b_hh[lane];

    float h = 1.0f; // h0 = ones

    // x for this sample: [T][I] contiguous; address is wave-uniform.
    const float4* xs4 = (const float4*)(x + (size_t)n * (RT * RI));

    float4 xc[RI / 4], xn[RI / 4];
#pragma unroll
    for (int u = 0; u < RI / 4; ++u) xc[u] = xs4[u];

    for (int t = 0; t < RT; ++t) {
        const int tn = (t + 1 < RT) ? (t + 1) : t;
        // prefetch next step's x (uniform -> s_load, scalar pipe)
#pragma unroll
        for (int u = 0; u < RI / 4; ++u) xn[u] = xs4[tn * (RI / 4) + u];

        f32x2 acc[4];
        acc[0] = f32x2{bias, 0.0f};
        acc[1] = f32x2{0.0f, 0.0f};
        acc[2] = f32x2{0.0f, 0.0f};
        acc[3] = f32x2{0.0f, 0.0f};

        // x part: pairs live adjacently in the (scalar) float4s
#pragma unroll
        for (int u = 0; u < RI / 4; ++u) {
            acc[(2 * u) & 3]     += wih[2 * u]     * f32x2{xc[u].x, xc[u].y};
            acc[(2 * u + 1) & 3] += wih[2 * u + 1] * f32x2{xc[u].z, xc[u].w};
        }
        // h part: broadcast h pairs with 2 readlanes, pk_fma against W_hh rows
#pragma unroll
        for (int q = 0; q < RH / 2; ++q) {
            f32x2 hb = f32x2{rl_f(h, 2 * q), rl_f(h, 2 * q + 1)};
            acc[q & 3] += whh[q] * hb;
        }
        f32x2 s2 = (acc[0] + acc[1]) + (acc[2] + acc[3]);
        float z = s2.x + s2.y;

        // tanh: 1 - 2/(e^{2z}+1); saturates correctly for large |z|
        float e = __expf(2.0f * z);
        h = 1.0f - __fdividef(2.0f, e + 1.0f);

#pragma unroll
        for (int u = 0; u < RI / 4; ++u) xc[u] = xn[u];
    }

    // ---- epilogue: sigmoid(h . fc_w + fc_b) ----
    float z = h * fc_w[lane];
#pragma unroll
    for (int off = 32; off > 0; off >>= 1)
        z += __shfl_down(z, off);
    if (lane == 0) {
        float logit = z + fc_b[0];
        out[n] = __fdividef(1.0f, 1.0f + __expf(-logit));
    }
}

extern "C" void kernel_launch(void* const* d_in, const int* in_sizes, int n_in,
                              void* d_out, int out_size, void* d_ws, size_t ws_size,
                              hipStream_t stream) {
    rnn_fused<<<RN / 4, 256, 0, stream>>>(
        (const float*)d_in[0], (const float*)d_in[1], (const float*)d_in[2],
        (const float*)d_in[3], (const float*)d_in[4], (const float*)d_in[5],
        (const float*)d_in[6], (float*)d_out);
}